// Round 1
// baseline (1199.076 us; speedup 1.0000x reference)
//
#include <hip/hip_runtime.h>
#include <math.h>

#define B_ 2
#define C_ 4
#define N_ 224
#define V_ 7
#define W_ 256
#define S_ 1792
#define EMB_ 256
#define H_ 4
#define D_ 64
#define TOK_ 896
#define HF_ 10

// ---------------- generic strided batched GEMM: C[m,n] = sum_k A[m,k]*B[k,n] ----------------
__global__ void gemm_kernel(const float* __restrict__ A, const float* __restrict__ Bm,
                            float* __restrict__ Cm,
                            int M, int N, int K,
                            int as_m, int as_k, int bs_k, int bs_n,
                            int cs_m, int cs_n,
                            long a_bs, long b_bs, long c_bs)
{
    int batch = blockIdx.z;
    A  += (long)batch * a_bs;
    Bm += (long)batch * b_bs;
    Cm += (long)batch * c_bs;
    __shared__ float As[16][17], Bs[16][17];
    int tm = threadIdx.y, tn = threadIdx.x;
    int m = blockIdx.y * 16 + tm;
    int n = blockIdx.x * 16 + tn;
    float acc = 0.f;
    for (int k0 = 0; k0 < K; k0 += 16) {
        int ka = k0 + tn;
        As[tm][tn] = (m < M && ka < K) ? A[(long)m * as_m + (long)ka * as_k] : 0.f;
        int kb = k0 + tm;
        Bs[tm][tn] = (kb < K && n < N) ? Bm[(long)kb * bs_k + (long)n * bs_n] : 0.f;
        __syncthreads();
        #pragma unroll
        for (int kk = 0; kk < 16; ++kk) acc += As[tm][kk] * Bs[kk][tn];
        __syncthreads();
    }
    if (m < M && n < N) Cm[(long)m * cs_m + (long)n * cs_n] = acc;
}

// ---------------- LayerNorm over channel dim, layout [img, Cch, S] ----------------
__global__ void ln_ch_kernel(const float* __restrict__ X, const float* __restrict__ g,
                             const float* __restrict__ b, float* __restrict__ Y,
                             int Cch, int S)
{
    int s = blockIdx.x * blockDim.x + threadIdx.x;
    if (s >= S) return;
    int img = blockIdx.y;
    const float* xp = X + (long)img * Cch * S + s;
    float sum = 0.f, sumsq = 0.f;
    for (int c = 0; c < Cch; ++c) { float v = xp[(long)c * S]; sum += v; sumsq += v * v; }
    float mean = sum / Cch;
    float var  = sumsq / Cch - mean * mean;
    float inv  = rsqrtf(var + 1e-6f);
    float* yp = Y + (long)img * Cch * S + s;
    for (int c = 0; c < Cch; ++c)
        yp[(long)c * S] = (xp[(long)c * S] - mean) * inv * g[c] + b[c];
}

// ---------------- depthwise 3x3, SAME, spatial V_ x W_ ----------------
__global__ void dwconv3_kernel(const float* __restrict__ X, const float* __restrict__ Wt,
                               float* __restrict__ Y, long total, int Ch)
{
    long idx = (long)blockIdx.x * blockDim.x + threadIdx.x;
    long stride = (long)gridDim.x * blockDim.x;
    for (; idx < total; idx += stride) {
        int w = (int)(idx % W_);
        long t = idx / W_;
        int h = (int)(t % V_); t /= V_;
        int ch = (int)(t % Ch);
        long img_ch = idx / ((long)V_ * W_);
        const float* wp = Wt + ch * 9;
        const float* xp = X + img_ch * (V_ * W_);
        float acc = 0.f;
        #pragma unroll
        for (int dy = -1; dy <= 1; ++dy) {
            int h2 = h + dy;
            if (h2 < 0 || h2 >= V_) continue;
            #pragma unroll
            for (int dx = -1; dx <= 1; ++dx) {
                int w2 = w + dx;
                if (w2 < 0 || w2 >= W_) continue;
                acc += xp[h2 * W_ + w2] * wp[(dy + 1) * 3 + (dx + 1)];
            }
        }
        Y[idx] = acc;
    }
}

// ---------------- head transpose + L2 normalize (q/k) + temperature fold (q) ----------------
// src: [B_, 768, S_]; dst: [B_, H_, S_, D_]; mode 0=v copy, 1=k 1/norm, 2=q temp/norm
__global__ void headnorm_kernel(const float* __restrict__ src, float* __restrict__ dst,
                                const float* __restrict__ temp, int chbase, int mode)
{
    int idx = blockIdx.x * blockDim.x + threadIdx.x;   // (b*H+h)*S + s
    if (idx >= B_ * H_ * S_) return;
    int s  = idx % S_;
    int bh = idx / S_;
    int h  = bh % H_;
    int b  = bh / H_;
    const float* sp = src + ((long)b * 768 + chbase + h * D_) * S_ + s;
    float scale = 1.f;
    if (mode != 0) {
        float ss = 0.f;
        for (int dd = 0; dd < D_; ++dd) { float v = sp[(long)dd * S_]; ss += v * v; }
        float nrm = fmaxf(sqrtf(ss), 1e-12f);
        scale = 1.f / nrm;
        if (mode == 2) scale *= temp[h];
    }
    float* dp = dst + (long)idx * D_;
    for (int dd = 0; dd < D_; ++dd) dp[dd] = sp[(long)dd * S_] * scale;
}

// ---------------- softmax row stats over j ----------------
__global__ void rowstats_kernel(const float* __restrict__ L, float* __restrict__ rmax,
                                float* __restrict__ rsum)
{
    int row = blockIdx.x;              // (b*H+h)*S + i
    const float* rp = L + (long)row * S_;
    __shared__ float red[256];
    int t = threadIdx.x;
    float m = -1e30f;
    for (int j = t; j < S_; j += 256) m = fmaxf(m, rp[j]);
    red[t] = m; __syncthreads();
    for (int o = 128; o > 0; o >>= 1) { if (t < o) red[t] = fmaxf(red[t], red[t + o]); __syncthreads(); }
    float rowm = red[0]; __syncthreads();
    float sm = 0.f;
    for (int j = t; j < S_; j += 256) sm += expf(rp[j] - rowm);
    red[t] = sm; __syncthreads();
    for (int o = 128; o > 0; o >>= 1) { if (t < o) red[t] += red[t + o]; __syncthreads(); }
    if (t == 0) { rmax[row] = rowm; rsum[row] = red[0]; }
}

// ---------------- fused softmax + relu^2*gelu + head-mix, in place on L ----------------
__global__ void attnmix_kernel(float* __restrict__ L, const float* __restrict__ rmax,
                               const float* __restrict__ rsum, const float* __restrict__ wat)
{
    long idx = (long)blockIdx.x * blockDim.x + threadIdx.x;
    long total = (long)B_ * S_ * S_;
    if (idx >= total) return;
    int j = (int)(idx % S_);
    long t2 = idx / S_;
    int i = (int)(t2 % S_);
    int b = (int)(t2 / S_);
    float a0[H_], a1[H_];
    #pragma unroll
    for (int h = 0; h < H_; ++h) {
        long off = (((long)(b * H_ + h)) * S_ + i) * S_ + j;
        float l = L[off];
        int row = (b * H_ + h) * S_ + i;
        a0[h] = expf(l - rmax[row]) / rsum[row];
        float r = fmaxf(l, 0.f);
        float s1 = r * r;
        float gl = 0.5f * s1 * (1.f + erff(s1 * 0.70710678118f));
        a1[h] = gl * s1;
    }
    #pragma unroll
    for (int h = 0; h < H_; ++h) {
        float sc = 0.f, sh = 0.f;
        #pragma unroll
        for (int hh = 0; hh < H_; ++hh) {
            sc += a1[hh] * wat[h * H_ + hh];
            sh += a1[hh] * wat[(H_ + h) * H_ + hh];
        }
        long off = (((long)(b * H_ + h)) * S_ + i) * S_ + j;
        L[off] = a0[h] * (1.f + sc) + sh;
    }
}

// ---------------- residual add (remapped) + LN over C=4 ----------------
__global__ void resid_ln2_kernel(const float* __restrict__ buf, const float* __restrict__ proj,
                                 const float* __restrict__ g2, const float* __restrict__ b2,
                                 float* __restrict__ x2, float* __restrict__ epiln)
{
    int s = blockIdx.x * blockDim.x + threadIdx.x;
    if (s >= S_) return;
    int bn = blockIdx.y;
    int b = bn / N_, n = bn % N_;
    float v[C_];
    float sum = 0.f;
    #pragma unroll
    for (int c = 0; c < C_; ++c) {
        float xr = buf[(((long)(b * C_ + c)) * N_ + n) * S_ + s];
        float pr = proj[((long)b * TOK_ + c * N_ + n) * S_ + s];
        v[c] = xr + pr;
        x2[((long)bn * C_ + c) * S_ + s] = v[c];
        sum += v[c];
    }
    float mean = sum / C_;
    float var = 0.f;
    #pragma unroll
    for (int c = 0; c < C_; ++c) { float d = v[c] - mean; var += d * d; }
    var /= C_;
    float inv = rsqrtf(var + 1e-6f);
    #pragma unroll
    for (int c = 0; c < C_; ++c)
        epiln[((long)bn * C_ + c) * S_ + s] = (v[c] - mean) * inv * g2[c] + b2[c];
}

// ---------------- GDFN gating: g = gelu(h1) * h2 ----------------
__global__ void gelumul_kernel(const float* __restrict__ hd, float* __restrict__ g)
{
    long idx = (long)blockIdx.x * blockDim.x + threadIdx.x;
    long total = (long)(B_ * N_) * HF_ * S_;
    if (idx >= total) return;
    int s = (int)(idx % S_);
    long t = idx / S_;
    int f = (int)(t % HF_);
    long bn = t / HF_;
    float h1 = hd[((long)bn * (2 * HF_) + f) * S_ + s];
    float h2 = hd[((long)bn * (2 * HF_) + HF_ + f) * S_ + s];
    float gl = 0.5f * h1 * (1.f + erff(h1 * 0.70710678118f));
    g[idx] = gl * h2;
}

// ---------------- final residual + output remap to [B,C,N,V,W] ----------------
__global__ void finaladd_kernel(const float* __restrict__ x2, const float* __restrict__ pout,
                                float* __restrict__ out)
{
    long idx = (long)blockIdx.x * blockDim.x + threadIdx.x;
    long total = (long)B_ * C_ * N_ * S_;
    if (idx >= total) return;
    int s = (int)(idx % S_);
    long t = idx / S_;
    int n = (int)(t % N_); t /= N_;
    int c = (int)(t % C_);
    int b = (int)(t / C_);
    long r = (((long)(b * N_ + n)) * C_ + c) * S_ + s;
    out[idx] = x2[r] + pout[r];
}

static inline void launch_gemm(const float* A, const float* Bm, float* Cm,
                               int M, int N, int K,
                               int as_m, int as_k, int bs_k, int bs_n,
                               int cs_m, int cs_n,
                               long a_bs, long b_bs, long c_bs, int batch,
                               hipStream_t st)
{
    dim3 grid((N + 15) / 16, (M + 15) / 16, batch);
    gemm_kernel<<<grid, dim3(16, 16), 0, st>>>(A, Bm, Cm, M, N, K,
                                               as_m, as_k, bs_k, bs_n, cs_m, cs_n,
                                               a_bs, b_bs, c_bs);
}

extern "C" void kernel_launch(void* const* d_in, const int* in_sizes, int n_in,
                              void* d_out, int out_size, void* d_ws, size_t ws_size,
                              hipStream_t stream)
{
    const float* buffer = (const float*)d_in[0];
    const float* w_in   = (const float*)d_in[1];
    const float* temp   = (const float*)d_in[2];
    const float* ln1_g  = (const float*)d_in[3];
    const float* ln1_b  = (const float*)d_in[4];
    const float* w_qkv  = (const float*)d_in[5];
    const float* w_qkv_dw = (const float*)d_in[6];
    const float* w_proj = (const float*)d_in[7];
    const float* w_attca = (const float*)d_in[8];
    const float* ln2_g  = (const float*)d_in[9];
    const float* ln2_b  = (const float*)d_in[10];
    const float* w_pin  = (const float*)d_in[11];
    const float* w_dw   = (const float*)d_in[12];
    const float* w_pout = (const float*)d_in[13];
    float* out = (float*)d_out;

    float* ws = (float*)d_ws;
    // region P0 (25,690,112 floats) with lifetime-based reuse
    float* P0     = ws;
    float* xw     = P0;                 //   917,504  [B,256,S]
    float* xn     = P0 + 917504;        //   917,504
    float* qkv    = P0 + 1835008;       // 2,752,512  [B,768,S]
    float* qkvd   = P0 + 4587520;       // 2,752,512
    float* L      = P0;                 // 25,690,112 [B,H,S,S] (after qkvd dead)
    float* outproj= P0;                 // 3,211,264  [B,896,S] (after L dead)
    float* x2     = P0 + 3211264;       // 3,211,264  [448,4,S]
    float* epiln  = P0 + 6422528;       // 3,211,264
    float* hbuf   = P0 + 9633792;       // 16,056,320 [448,20,S]
    float* gbuf   = P0 + 9633792;       // 8,028,160  [448,10,S] (after hbuf dead)
    float* P8     = ws + 25690112;
    float* hd     = P8;                 // 16,056,320
    float* pout   = P8;                 // 3,211,264  (after hd dead)
    float* P1     = ws + 41746432;
    float* qn     = P1;                 //   917,504  [B,H,S,64]
    float* kn     = P1 + 917504;
    float* vt     = P1 + 1835008;
    float* P2     = ws + 44498944;
    float* rmax   = P2;                 //    14,336
    float* rsum   = P2 + 14336;
    float* outav  = ws + 44527616;      //   917,504  [B,256,S] image layout
    // total: 45,445,120 floats = 181.8 MB

    // 1. linear_in: xw[b,e,s] = sum_k w_in[e,k] * buffer_view[b,k,s]
    launch_gemm(w_in, buffer, xw, EMB_, S_, TOK_,
                TOK_, 1,  S_, 1,  S_, 1,
                0L, (long)TOK_ * S_, (long)EMB_ * S_, B_, stream);

    // 2. LN1 over 256 channels
    ln_ch_kernel<<<dim3(7, B_), 256, 0, stream>>>(xw, ln1_g, ln1_b, xn, EMB_, S_);

    // 3. qkv 1x1 conv
    launch_gemm(w_qkv, xn, qkv, 3 * EMB_, S_, EMB_,
                EMB_, 1,  S_, 1,  S_, 1,
                0L, (long)EMB_ * S_, (long)3 * EMB_ * S_, B_, stream);

    // 4. depthwise 3x3 on qkv
    {
        long total = (long)B_ * 3 * EMB_ * S_;
        int blocks = (int)((total + 255) / 256);
        dwconv3_kernel<<<blocks, 256, 0, stream>>>(qkv, w_qkv_dw, qkvd, total, 3 * EMB_);
    }

    // 5. head transpose + normalize (temp folded into q)
    {
        int blocks = (B_ * H_ * S_ + 255) / 256;
        headnorm_kernel<<<blocks, 256, 0, stream>>>(qkvd, vt, temp, 2 * EMB_, 0);
        headnorm_kernel<<<blocks, 256, 0, stream>>>(qkvd, kn, temp, EMB_, 1);
        headnorm_kernel<<<blocks, 256, 0, stream>>>(qkvd, qn, temp, 0, 2);
    }

    // 6. attention logits L = qn @ kn^T   [per (b,h): S x S, K=64]
    launch_gemm(qn, kn, L, S_, S_, D_,
                D_, 1,  1, D_,  S_, 1,
                (long)S_ * D_, (long)S_ * D_, (long)S_ * S_, B_ * H_, stream);

    // 7. softmax row stats
    rowstats_kernel<<<B_ * H_ * S_, 256, 0, stream>>>(L, rmax, rsum);

    // 8. fused softmax + relu^2-gelu + head-mix (in place)
    {
        long total = (long)B_ * S_ * S_;
        int blocks = (int)((total + 255) / 256);
        attnmix_kernel<<<blocks, 256, 0, stream>>>(L, rmax, rsum, w_attca);
    }

    // 9. out = attn @ v, written directly to image layout [B,256,S]
    launch_gemm(L, vt, outav, S_, D_, S_,
                S_, 1,  D_, 1,  1, S_,
                (long)S_ * S_, (long)S_ * D_, (long)D_ * S_, B_ * H_, stream);

    // 10. proj to token dim
    launch_gemm(w_proj, outav, outproj, TOK_, S_, EMB_,
                EMB_, 1,  S_, 1,  S_, 1,
                0L, (long)EMB_ * S_, (long)TOK_ * S_, B_, stream);

    // 11. residual add (remap) + LN2 over C=4
    resid_ln2_kernel<<<dim3(7, B_ * N_), 256, 0, stream>>>(buffer, outproj, ln2_g, ln2_b, x2, epiln);

    // 12. GDFN pin: [20 x 4] x [4 x S] per image
    launch_gemm(w_pin, epiln, hbuf, 2 * HF_, S_, C_,
                C_, 1,  S_, 1,  S_, 1,
                0L, (long)C_ * S_, (long)2 * HF_ * S_, B_ * N_, stream);

    // 13. depthwise 3x3 on h
    {
        long total = (long)B_ * N_ * 2 * HF_ * S_;
        int blocks = (int)((total + 255) / 256);
        dwconv3_kernel<<<blocks, 256, 0, stream>>>(hbuf, w_dw, hd, total, 2 * HF_);
    }

    // 14. g = gelu(h1) * h2
    {
        long total = (long)B_ * N_ * HF_ * S_;
        int blocks = (int)((total + 255) / 256);
        gelumul_kernel<<<blocks, 256, 0, stream>>>(hd, gbuf);
    }

    // 15. GDFN pout: [4 x 10] x [10 x S] per image
    launch_gemm(w_pout, gbuf, pout, C_, S_, HF_,
                HF_, 1,  S_, 1,  S_, 1,
                0L, (long)HF_ * S_, (long)C_ * S_, B_ * N_, stream);

    // 16. final residual + output remap
    {
        long total = (long)B_ * C_ * N_ * S_;
        int blocks = (int)((total + 255) / 256);
        finaladd_kernel<<<blocks, 256, 0, stream>>>(x2, pout, out);
    }
}

// Round 2
// 431.045 us; speedup vs baseline: 2.7818x; 2.7818x over previous
//
#include <hip/hip_runtime.h>
#include <math.h>

#define B_ 2
#define C_ 4
#define N_ 224
#define V_ 7
#define W_ 256
#define S_ 1792
#define EMB_ 256
#define H_ 4
#define D_ 64
#define TOK_ 896
#define HF_ 10
#define JC_ 4
#define JRANGE_ (S_ / JC_)      /* 448 */
#define JSTEPS_ (JRANGE_ / 32)  /* 14 */

typedef __attribute__((ext_vector_type(8))) short short8;
typedef __attribute__((ext_vector_type(4))) float f32x4;

#define MFMA16(a, b, c) __builtin_amdgcn_mfma_f32_16x16x32_bf16(a, b, c, 0, 0, 0)

__device__ inline short f2bf(float f) {
    union { float f; unsigned u; } x; x.f = f;
    unsigned u = x.u;
    unsigned r = (u + 0x7fffu + ((u >> 16) & 1u)) >> 16;
    return (short)r;
}

// ---------------- fp32 register-tiled GEMM: C[b][M][N] = A[M][K] * B[b][K][N] ----------------
__global__ __launch_bounds__(256) void gemm64_kernel(
    const float* __restrict__ A, const float* __restrict__ Bm, float* __restrict__ Cm,
    int M, int N, int K, long b_bs, long c_bs)
{
    Bm += (long)blockIdx.z * b_bs;
    Cm += (long)blockIdx.z * c_bs;
    __shared__ float As[16][68], Bs[16][68];
    int t = threadIdx.x;
    int tx = t & 15, ty = t >> 4;
    int m0 = blockIdx.y * 64, n0 = blockIdx.x * 64;
    int arow = t >> 4, acol = t & 15;
    float acc[4][4] = {};
    for (int k0 = 0; k0 < K; k0 += 16) {
        #pragma unroll
        for (int i = 0; i < 4; ++i)
            As[acol][arow + i * 16] = A[(long)(m0 + arow + i * 16) * K + k0 + acol];
        #pragma unroll
        for (int i = 0; i < 4; ++i) {
            int e = t + i * 256;
            Bs[e >> 6][e & 63] = Bm[(long)(k0 + (e >> 6)) * N + n0 + (e & 63)];
        }
        __syncthreads();
        #pragma unroll
        for (int kk = 0; kk < 16; ++kk) {
            f32x4 av = *(const f32x4*)&As[kk][ty * 4];
            f32x4 bv = *(const f32x4*)&Bs[kk][tx * 4];
            #pragma unroll
            for (int i = 0; i < 4; ++i)
                #pragma unroll
                for (int j = 0; j < 4; ++j)
                    acc[i][j] += av[i] * bv[j];
        }
        __syncthreads();
    }
    #pragma unroll
    for (int i = 0; i < 4; ++i) {
        f32x4 cv;
        #pragma unroll
        for (int j = 0; j < 4; ++j) cv[j] = acc[i][j];
        *(f32x4*)&Cm[(long)(m0 + ty * 4 + i) * N + n0 + tx * 4] = cv;
    }
}

// ---------------- LayerNorm over channel dim, layout [img, Cch, S] ----------------
__global__ void ln_ch_kernel(const float* __restrict__ X, const float* __restrict__ g,
                             const float* __restrict__ b, float* __restrict__ Y,
                             int Cch, int S)
{
    int s = blockIdx.x * blockDim.x + threadIdx.x;
    if (s >= S) return;
    int img = blockIdx.y;
    const float* xp = X + (long)img * Cch * S + s;
    float sum = 0.f, sumsq = 0.f;
    for (int c = 0; c < Cch; ++c) { float v = xp[(long)c * S]; sum += v; sumsq += v * v; }
    float mean = sum / Cch;
    float var  = sumsq / Cch - mean * mean;
    float inv  = rsqrtf(var + 1e-6f);
    float* yp = Y + (long)img * Cch * S + s;
    for (int c = 0; c < Cch; ++c)
        yp[(long)c * S] = (xp[(long)c * S] - mean) * inv * g[c] + b[c];
}

// ---------------- depthwise 3x3, SAME, spatial V_ x W_ ----------------
__global__ void dwconv3_kernel(const float* __restrict__ X, const float* __restrict__ Wt,
                               float* __restrict__ Y, long total, int Ch)
{
    long idx = (long)blockIdx.x * blockDim.x + threadIdx.x;
    long stride = (long)gridDim.x * blockDim.x;
    for (; idx < total; idx += stride) {
        int w = (int)(idx % W_);
        long t = idx / W_;
        int h = (int)(t % V_); t /= V_;
        int ch = (int)(t % Ch);
        long img_ch = idx / ((long)V_ * W_);
        const float* wp = Wt + ch * 9;
        const float* xp = X + img_ch * (V_ * W_);
        float acc = 0.f;
        #pragma unroll
        for (int dy = -1; dy <= 1; ++dy) {
            int h2 = h + dy;
            if (h2 < 0 || h2 >= V_) continue;
            #pragma unroll
            for (int dx = -1; dx <= 1; ++dx) {
                int w2 = w + dx;
                if (w2 < 0 || w2 >= W_) continue;
                acc += xp[h2 * W_ + w2] * wp[(dy + 1) * 3 + (dx + 1)];
            }
        }
        Y[idx] = acc;
    }
}

// ------- head transpose + L2-normalize -> bf16 [B][H][S][64]; q also scaled by temp -------
__global__ __launch_bounds__(256) void headnorm_kernel(
    const float* __restrict__ qkvd, const float* __restrict__ temp,
    short* __restrict__ qn, short* __restrict__ kn)
{
    int s0 = blockIdx.x * 64;
    int bh = blockIdx.y; int b = bh >> 2, h = bh & 3;
    int isq = blockIdx.z;                    // 0 = k, 1 = q
    int ch0 = b * 768 + (isq ? 0 : EMB_) + h * 64;
    short* dst = (isq ? qn : kn) + (long)bh * S_ * 64;
    __shared__ float tile[64][65];
    __shared__ float red[64][4];
    int t = threadIdx.x;
    int sl = t & 63, dg = t >> 6;
    float part = 0.f;
    for (int dd = 0; dd < 16; ++dd) {
        int d = dg * 16 + dd;
        float v = qkvd[(long)(ch0 + d) * S_ + s0 + sl];
        tile[sl][d] = v;
        part += v * v;
    }
    red[sl][dg] = part;
    __syncthreads();
    int d = t & 63, sg = t >> 6;
    float tmul = isq ? temp[h] : 1.f;
    for (int si = 0; si < 16; ++si) {
        int s = sg * 16 + si;
        float nrm = sqrtf(red[s][0] + red[s][1] + red[s][2] + red[s][3]);
        float scale = tmul / fmaxf(nrm, 1e-12f);
        dst[(long)(s0 + s) * 64 + d] = f2bf(tile[s][d] * scale);
    }
}

// ---------------- fused attention: QK^T (MFMA) + mix + AV (MFMA), j-split partials ----------------
__global__ __launch_bounds__(256) void attn_kernel(
    const short* __restrict__ qn, const short* __restrict__ kn,
    const float* __restrict__ qkvd, const float* __restrict__ wat,
    float* __restrict__ partY, float* __restrict__ partZ)
{
    int h = threadIdx.x >> 6;                 // wave = head
    int lane = threadIdx.x & 63;
    int col = lane & 15, grp = lane >> 4;
    int itile = blockIdx.x;                   // 0..111
    int jc = blockIdx.y;                      // 0..3
    int b = blockIdx.z;
    int ibase = itile * 16;
    int bh = b * 4 + h;

    const short* qrow = qn + ((long)bh * S_ + ibase + col) * 64 + grp * 8;
    short8 qa0 = *(const short8*)qrow;
    short8 qa1 = *(const short8*)(qrow + 32);
    float wsc[4], wsh[4];
    #pragma unroll
    for (int hh = 0; hh < 4; ++hh) { wsc[hh] = wat[h * 4 + hh]; wsh[hh] = wat[(4 + h) * 4 + hh]; }

    __shared__ __align__(16) float exch[4][16][33];
    __shared__ __align__(16) short pbuf[4][2][16][40];

    f32x4 y1[4], y2[4];
    #pragma unroll
    for (int ds = 0; ds < 4; ++ds) {
        y1[ds] = (f32x4){0.f, 0.f, 0.f, 0.f};
        y2[ds] = (f32x4){0.f, 0.f, 0.f, 0.f};
    }
    float zp[4] = {0.f, 0.f, 0.f, 0.f};
    const short* kbase = kn + (long)bh * S_ * 64;
    const float* vbase = qkvd + ((long)b * 768 + 512 + h * 64) * S_;

    for (int jt = 0; jt < JSTEPS_; ++jt) {
        int jbase = jc * JRANGE_ + jt * 32;
        f32x4 lf[2];
        #pragma unroll
        for (int js = 0; js < 2; ++js) {
            const short* krow = kbase + (long)(jbase + js * 16 + col) * 64 + grp * 8;
            short8 kb0 = *(const short8*)krow;
            short8 kb1 = *(const short8*)(krow + 32);
            f32x4 a = (f32x4){0.f, 0.f, 0.f, 0.f};
            a = MFMA16(qa0, kb0, a);
            a = MFMA16(qa1, kb1, a);
            lf[js] = a;
        }
        // own-head a1 = gelu(relu(l)^2)*relu(l)^2, exchanged via LDS (computed once per h,i,j)
        float a1own[8];
        #pragma unroll
        for (int js = 0; js < 2; ++js)
            #pragma unroll
            for (int r = 0; r < 4; ++r) {
                float l = lf[js][r];
                float rr = fmaxf(l, 0.f);
                float s1 = rr * rr;
                float a1 = s1 * 0.5f * (1.f + erff(s1 * 0.70710678118654752f)) * s1;
                a1own[js * 4 + r] = a1;
                exch[h][grp * 4 + r][js * 16 + col] = a1;
            }
        __syncthreads();
        #pragma unroll
        for (int js = 0; js < 2; ++js)
            #pragma unroll
            for (int r = 0; r < 4; ++r) {
                float sc = 0.f, sh = 0.f;
                #pragma unroll
                for (int hh = 0; hh < 4; ++hh) {
                    float a1v = (hh == h) ? a1own[js * 4 + r]
                                          : exch[hh][grp * 4 + r][js * 16 + col];
                    sc += a1v * wsc[hh];
                    sh += a1v * wsh[hh];
                }
                float e = __expf(lf[js][r]);
                zp[r] += e;
                pbuf[h][0][grp * 4 + r][js * 16 + col] = f2bf(e * (1.f + sc));
                pbuf[h][1][grp * 4 + r][js * 16 + col] = f2bf(sh);
            }
        __syncthreads();
        short8 p1a = *(const short8*)&pbuf[h][0][col][grp * 8];
        short8 p2a = *(const short8*)&pbuf[h][1][col][grp * 8];
        #pragma unroll
        for (int ds = 0; ds < 4; ++ds) {
            const float* vrow = vbase + (long)(ds * 16 + col) * S_ + jbase + grp * 8;
            f32x4 v0 = *(const f32x4*)vrow;
            f32x4 v1 = *(const f32x4*)(vrow + 4);
            short8 vb;
            vb[0] = f2bf(v0[0]); vb[1] = f2bf(v0[1]); vb[2] = f2bf(v0[2]); vb[3] = f2bf(v0[3]);
            vb[4] = f2bf(v1[0]); vb[5] = f2bf(v1[1]); vb[6] = f2bf(v1[2]); vb[7] = f2bf(v1[3]);
            y1[ds] = MFMA16(p1a, vb, y1[ds]);
            y2[ds] = MFMA16(p2a, vb, y2[ds]);
        }
    }

    // Z: reduce over the 16 lanes covering the row's columns
    #pragma unroll
    for (int o = 1; o < 16; o <<= 1) {
        #pragma unroll
        for (int r = 0; r < 4; ++r) zp[r] += __shfl_xor(zp[r], o, 64);
    }
    if (col == 0) {
        #pragma unroll
        for (int r = 0; r < 4; ++r)
            partZ[((long)(jc * 2 + b) * 4 + h) * S_ + ibase + grp * 4 + r] = zp[r];
    }
    // transpose D-frags via LDS, write partY[jc][b][h][acc][d][i] coalesced over i
    float* tb = &exch[h][0][0];               // wave-private scratch, 16x17 layout
    long ybase = ((((long)jc * 2 + b) * 4 + h) * 2) * 64 * S_;
    for (int acc = 0; acc < 2; ++acc) {
        #pragma unroll
        for (int ds = 0; ds < 4; ++ds) {
            f32x4 y = acc ? y2[ds] : y1[ds];
            #pragma unroll
            for (int r = 0; r < 4; ++r) tb[col * 17 + grp * 4 + r] = y[r];
            #pragma unroll
            for (int p = 0; p < 4; ++p) {
                float val = tb[(p * 4 + grp) * 17 + col];
                partY[ybase + ((long)acc * 64 + ds * 16 + p * 4 + grp) * S_ + ibase + col] = val;
            }
        }
    }
}

// ---------------- combine j-chunks: out = (sum Y1)/(sum Z) + sum Y2 ----------------
__global__ __launch_bounds__(256) void combine_kernel(
    const float* __restrict__ partY, const float* __restrict__ partZ,
    float* __restrict__ outav)
{
    int idx = blockIdx.x * 256 + threadIdx.x;   // ((b*4+h)*64+d)*S + i
    int i = idx % S_;
    int t = idx / S_;
    int d = t & 63; t >>= 6;
    int h = t & 3; int b = t >> 2;
    float y1 = 0.f, y2 = 0.f, z = 0.f;
    #pragma unroll
    for (int jc = 0; jc < JC_; ++jc) {
        long base = ((((long)jc * 2 + b) * 4 + h) * 2) * 64 * S_;
        y1 += partY[base + (long)d * S_ + i];
        y2 += partY[base + (long)(64 + d) * S_ + i];
        z  += partZ[((long)(jc * 2 + b) * 4 + h) * S_ + i];
    }
    outav[((long)b * 256 + h * 64 + d) * S_ + i] = y1 / z + y2;
}

// ---------------- residual add (remap) + LN2 over C=4 + GDFN pin ----------------
__global__ __launch_bounds__(256) void resid_pin_kernel(
    const float* __restrict__ buffer, const float* __restrict__ proj,
    const float* __restrict__ g2, const float* __restrict__ b2,
    const float* __restrict__ w_pin,
    float* __restrict__ x2, float* __restrict__ hbuf)
{
    int s = blockIdx.x * 256 + threadIdx.x;
    int bn = blockIdx.y;
    int b = bn / N_, n = bn % N_;
    float v[4];
    float sum = 0.f;
    #pragma unroll
    for (int c = 0; c < 4; ++c) {
        float xr = buffer[((long)(b * 4 + c) * N_ + n) * S_ + s];
        float pr = proj[((long)b * TOK_ + c * N_ + n) * S_ + s];
        v[c] = xr + pr;
        x2[((long)bn * 4 + c) * S_ + s] = v[c];
        sum += v[c];
    }
    float mean = sum * 0.25f;
    float var = 0.f;
    #pragma unroll
    for (int c = 0; c < 4; ++c) { float dd = v[c] - mean; var += dd * dd; }
    var *= 0.25f;
    float inv = rsqrtf(var + 1e-6f);
    float e[4];
    #pragma unroll
    for (int c = 0; c < 4; ++c) e[c] = (v[c] - mean) * inv * g2[c] + b2[c];
    for (int o = 0; o < 2 * HF_; ++o) {
        float a = 0.f;
        #pragma unroll
        for (int c = 0; c < 4; ++c) a += w_pin[o * 4 + c] * e[c];
        hbuf[((long)bn * (2 * HF_) + o) * S_ + s] = a;
    }
}

// ---------------- gelu(h1)*h2 + pout GEMM (K=10) + final residual + output remap ----------------
__global__ __launch_bounds__(256) void gdfn_out_kernel(
    const float* __restrict__ hd, const float* __restrict__ w_pout,
    const float* __restrict__ x2, float* __restrict__ out)
{
    int s = blockIdx.x * 256 + threadIdx.x;
    int bn = blockIdx.y;
    int b = bn / N_, n = bn % N_;
    float g[HF_];
    #pragma unroll
    for (int f = 0; f < HF_; ++f) {
        float h1 = hd[((long)bn * (2 * HF_) + f) * S_ + s];
        float h2 = hd[((long)bn * (2 * HF_) + HF_ + f) * S_ + s];
        g[f] = 0.5f * h1 * (1.f + erff(h1 * 0.70710678118654752f)) * h2;
    }
    #pragma unroll
    for (int c = 0; c < 4; ++c) {
        float a = 0.f;
        #pragma unroll
        for (int f = 0; f < HF_; ++f) a += w_pout[c * HF_ + f] * g[f];
        out[((long)(b * 4 + c) * N_ + n) * S_ + s] = x2[((long)bn * 4 + c) * S_ + s] + a;
    }
}

extern "C" void kernel_launch(void* const* d_in, const int* in_sizes, int n_in,
                              void* d_out, int out_size, void* d_ws, size_t ws_size,
                              hipStream_t stream)
{
    const float* buffer = (const float*)d_in[0];
    const float* w_in   = (const float*)d_in[1];
    const float* temp   = (const float*)d_in[2];
    const float* ln1_g  = (const float*)d_in[3];
    const float* ln1_b  = (const float*)d_in[4];
    const float* w_qkv  = (const float*)d_in[5];
    const float* w_qkv_dw = (const float*)d_in[6];
    const float* w_proj = (const float*)d_in[7];
    const float* w_attca = (const float*)d_in[8];
    const float* ln2_g  = (const float*)d_in[9];
    const float* ln2_b  = (const float*)d_in[10];
    const float* w_pin  = (const float*)d_in[11];
    const float* w_dw   = (const float*)d_in[12];
    const float* w_pout = (const float*)d_in[13];
    float* out = (float*)d_out;

    float* ws = (float*)d_ws;
    // lifetime-based layout (floats), total 38,535,168 = 154.1 MB
    float* qkvd    = ws;                       // [0 .. 2,752,512)
    short* qn      = (short*)(ws + 2752512);   // 917,504 bf16
    short* kn      = (short*)(ws + 3211264);   // 917,504 bf16
    float* partY   = ws + 3670016;             // 7,340,032
    float* partZ   = ws + 11010048;            // 57,344
    float* outav   = ws + 11067392;            // 917,504
    float* xw      = ws + 11067392;            // alias outav (dead before combine)
    float* xn      = ws + 16056320;            // alias outproj slot (dead before proj)
    float* outproj = ws + 16056320;            // 3,211,264
    float* qkv     = ws + 19267584;            // alias x2 slot (dead before resid_pin)
    float* x2      = ws + 19267584;            // 3,211,264
    float* hbuf    = ws;                       // [0 .. 16,056,320) after attention dead
    float* hd      = ws + 22478848;            // 16,056,320

    // 1. linear_in: xw[b][256][S] = w_in[256][896] x buffer_view[b][896][S]
    gemm64_kernel<<<dim3(28, 4, 2), 256, 0, stream>>>(
        w_in, buffer, xw, EMB_, S_, TOK_, (long)TOK_ * S_, (long)EMB_ * S_);

    // 2. LN1 over 256 channels
    ln_ch_kernel<<<dim3(7, B_), 256, 0, stream>>>(xw, ln1_g, ln1_b, xn, EMB_, S_);

    // 3. qkv 1x1 conv
    gemm64_kernel<<<dim3(28, 12, 2), 256, 0, stream>>>(
        w_qkv, xn, qkv, 3 * EMB_, S_, EMB_, (long)EMB_ * S_, (long)3 * EMB_ * S_);

    // 4. depthwise 3x3 on qkv
    {
        long total = (long)B_ * 3 * EMB_ * S_;
        dwconv3_kernel<<<(int)((total + 255) / 256), 256, 0, stream>>>(
            qkv, w_qkv_dw, qkvd, total, 3 * EMB_);
    }

    // 5. q,k -> normalized bf16 [B][H][S][64] (temp folded into q)
    headnorm_kernel<<<dim3(28, 8, 2), 256, 0, stream>>>(qkvd, temp, qn, kn);

    // 6. fused attention (MFMA): partials per j-chunk
    attn_kernel<<<dim3(112, JC_, B_), 256, 0, stream>>>(qn, kn, qkvd, w_attca, partY, partZ);

    // 7. combine partials -> outav [B][256][S]
    combine_kernel<<<3584, 256, 0, stream>>>(partY, partZ, outav);

    // 8. proj to token dim
    gemm64_kernel<<<dim3(28, 14, 2), 256, 0, stream>>>(
        w_proj, outav, outproj, TOK_, S_, EMB_, (long)EMB_ * S_, (long)TOK_ * S_);

    // 9. residual + LN2 + GDFN pin
    resid_pin_kernel<<<dim3(7, B_ * N_), 256, 0, stream>>>(
        buffer, outproj, ln2_g, ln2_b, w_pin, x2, hbuf);

    // 10. depthwise 3x3 on h (20 ch)
    {
        long total = (long)B_ * N_ * 2 * HF_ * S_;
        dwconv3_kernel<<<(int)((total + 255) / 256), 256, 0, stream>>>(
            hbuf, w_dw, hd, total, 2 * HF_);
    }

    // 11. gelu-gate + pout + final residual + remap
    gdfn_out_kernel<<<dim3(7, B_ * N_), 256, 0, stream>>>(hd, w_pout, x2, out);
}

// Round 3
// 281.926 us; speedup vs baseline: 4.2532x; 1.5289x over previous
//
#include <hip/hip_runtime.h>
#include <math.h>

#define B_ 2
#define C_ 4
#define N_ 224
#define V_ 7
#define W_ 256
#define S_ 1792
#define EMB_ 256
#define H_ 4
#define D_ 64
#define TOK_ 896
#define HF_ 10
#define JC_ 2
#define JRANGE_ (S_ / JC_)      /* 896 */
#define JSTEPS_ (JRANGE_ / 32)  /* 28 */

typedef __attribute__((ext_vector_type(8))) short short8;
typedef __attribute__((ext_vector_type(4))) short bf16x4;
typedef __attribute__((ext_vector_type(4))) float f32x4;

#define MFMA16(a, b, c) __builtin_amdgcn_mfma_f32_16x16x32_bf16(a, b, c, 0, 0, 0)

__device__ inline short f2bf(float f) {
    union { float f; unsigned u; } x; x.f = f;
    unsigned u = x.u;
    unsigned r = (u + 0x7fffu + ((u >> 16) & 1u)) >> 16;
    return (short)r;
}
__device__ inline float bf2f(short s) {
    union { unsigned u; float f; } x;
    x.u = ((unsigned)(unsigned short)s) << 16;
    return x.f;
}

// ------------- bf16 MFMA GEMM: C[b][M][N] = A[M][K](fp32) x Bact[b][K][N](fp32) -------------
// 128x128 tile, BK=32, 4 waves (2x2), reg-staged fp32->bf16 conversion, B transposed in LDS.
__global__ __launch_bounds__(256) void gemm_mfma_kernel(
    const float* __restrict__ A, const float* __restrict__ Bact, float* __restrict__ Cm,
    int M, int N, int K, long b_bs, long c_bs)
{
    Bact += (long)blockIdx.z * b_bs;
    Cm   += (long)blockIdx.z * c_bs;
    const int m0 = blockIdx.y * 128, n0 = blockIdx.x * 128;
    __shared__ __align__(16) short As[128][40];   // [m][k], pad 32->40
    __shared__ __align__(16) short Bs[128][40];   // [n][k], pad 32->40
    const int t = threadIdx.x;
    const int lane = t & 63;
    const int wave = t >> 6;
    const int wr = wave >> 1, wc = wave & 1;
    const int col = lane & 15, grp = lane >> 4;
    const int ar = t >> 3, ak = (t & 7) * 4;
    const int bn = t & 127, kb = (t >> 7) * 16;
    f32x4 acc[4][4];
    #pragma unroll
    for (int i = 0; i < 4; ++i)
        #pragma unroll
        for (int j = 0; j < 4; ++j) acc[i][j] = (f32x4){0.f, 0.f, 0.f, 0.f};
    for (int k0 = 0; k0 < K; k0 += 32) {
        #pragma unroll
        for (int p = 0; p < 4; ++p) {
            f32x4 v = *(const f32x4*)&A[(long)(m0 + ar + p * 32) * K + k0 + ak];
            bf16x4 pk;
            pk[0] = f2bf(v[0]); pk[1] = f2bf(v[1]); pk[2] = f2bf(v[2]); pk[3] = f2bf(v[3]);
            *(bf16x4*)&As[ar + p * 32][ak] = pk;
        }
        float tv[16];
        #pragma unroll
        for (int j = 0; j < 16; ++j)
            tv[j] = Bact[(long)(k0 + kb + j) * N + n0 + bn];
        short8 b0, b1;
        #pragma unroll
        for (int j = 0; j < 8; ++j) { b0[j] = f2bf(tv[j]); b1[j] = f2bf(tv[8 + j]); }
        *(short8*)&Bs[bn][kb]     = b0;
        *(short8*)&Bs[bn][kb + 8] = b1;
        __syncthreads();
        short8 af[4], bfr[4];
        #pragma unroll
        for (int m16 = 0; m16 < 4; ++m16)
            af[m16] = *(const short8*)&As[wr * 64 + m16 * 16 + col][grp * 8];
        #pragma unroll
        for (int n16 = 0; n16 < 4; ++n16)
            bfr[n16] = *(const short8*)&Bs[wc * 64 + n16 * 16 + col][grp * 8];
        #pragma unroll
        for (int m16 = 0; m16 < 4; ++m16)
            #pragma unroll
            for (int n16 = 0; n16 < 4; ++n16)
                acc[m16][n16] = MFMA16(af[m16], bfr[n16], acc[m16][n16]);
        __syncthreads();
    }
    #pragma unroll
    for (int m16 = 0; m16 < 4; ++m16)
        #pragma unroll
        for (int n16 = 0; n16 < 4; ++n16)
            #pragma unroll
            for (int r = 0; r < 4; ++r)
                Cm[(long)(m0 + wr * 64 + m16 * 16 + grp * 4 + r) * N
                   + n0 + wc * 64 + n16 * 16 + col] = acc[m16][n16][r];
}

// ---------------- LN1 over 256 channels, parallel: block = 64 s-pos x 4 ch-groups ----------------
__global__ __launch_bounds__(256) void ln1_kernel(
    const float* __restrict__ X, const float* __restrict__ g,
    const float* __restrict__ b, float* __restrict__ Y)
{
    int sl = threadIdx.x & 63, dg = threadIdx.x >> 6;
    int s = blockIdx.x * 64 + sl;
    int img = blockIdx.y;
    const float* xp = X + (long)img * EMB_ * S_ + s;
    float sum = 0.f, sq = 0.f;
    for (int c = dg * 64; c < dg * 64 + 64; ++c) {
        float v = xp[(long)c * S_];
        sum += v; sq += v * v;
    }
    __shared__ float rs[64][5], rq[64][5];
    rs[sl][dg] = sum; rq[sl][dg] = sq;
    __syncthreads();
    float tot = rs[sl][0] + rs[sl][1] + rs[sl][2] + rs[sl][3];
    float tq  = rq[sl][0] + rq[sl][1] + rq[sl][2] + rq[sl][3];
    float mean = tot * (1.f / EMB_);
    float var  = tq * (1.f / EMB_) - mean * mean;
    float inv  = rsqrtf(var + 1e-6f);
    float* yp = Y + (long)img * EMB_ * S_ + s;
    for (int c = dg * 64; c < dg * 64 + 64; ++c)
        yp[(long)c * S_] = (xp[(long)c * S_] - mean) * inv * g[c] + b[c];
}

// ---------------- depthwise 3x3, SAME, spatial V_ x W_ ----------------
__global__ void dwconv3_kernel(const float* __restrict__ X, const float* __restrict__ Wt,
                               float* __restrict__ Y, long total, int Ch)
{
    long idx = (long)blockIdx.x * blockDim.x + threadIdx.x;
    long stride = (long)gridDim.x * blockDim.x;
    for (; idx < total; idx += stride) {
        int w = (int)(idx % W_);
        long t = idx / W_;
        int h = (int)(t % V_); t /= V_;
        int ch = (int)(t % Ch);
        long img_ch = idx / ((long)V_ * W_);
        const float* wp = Wt + ch * 9;
        const float* xp = X + img_ch * (V_ * W_);
        float acc = 0.f;
        #pragma unroll
        for (int dy = -1; dy <= 1; ++dy) {
            int h2 = h + dy;
            if (h2 < 0 || h2 >= V_) continue;
            #pragma unroll
            for (int dx = -1; dx <= 1; ++dx) {
                int w2 = w + dx;
                if (w2 < 0 || w2 >= W_) continue;
                acc += xp[h2 * W_ + w2] * wp[(dy + 1) * 3 + (dx + 1)];
            }
        }
        Y[idx] = acc;
    }
}

// ------- head transpose + L2-normalize -> bf16 [B][H][S][64]; q also scaled by temp -------
__global__ __launch_bounds__(256) void headnorm_kernel(
    const float* __restrict__ qkvd, const float* __restrict__ temp,
    short* __restrict__ qn, short* __restrict__ kn)
{
    int s0 = blockIdx.x * 64;
    int bh = blockIdx.y; int b = bh >> 2, h = bh & 3;
    int isq = blockIdx.z;                    // 0 = k, 1 = q
    int ch0 = b * 768 + (isq ? 0 : EMB_) + h * 64;
    short* dst = (isq ? qn : kn) + (long)bh * S_ * 64;
    __shared__ float tile[64][65];
    __shared__ float red[64][4];
    int t = threadIdx.x;
    int sl = t & 63, dg = t >> 6;
    float part = 0.f;
    for (int dd = 0; dd < 16; ++dd) {
        int d = dg * 16 + dd;
        float v = qkvd[(long)(ch0 + d) * S_ + s0 + sl];
        tile[sl][d] = v;
        part += v * v;
    }
    red[sl][dg] = part;
    __syncthreads();
    int d = t & 63, sg = t >> 6;
    float tmul = isq ? temp[h] : 1.f;
    for (int si = 0; si < 16; ++si) {
        int s = sg * 16 + si;
        float nrm = sqrtf(red[s][0] + red[s][1] + red[s][2] + red[s][3]);
        float scale = tmul / fmaxf(nrm, 1e-12f);
        dst[(long)(s0 + s) * 64 + d] = f2bf(tile[s][d] * scale);
    }
}

// ---------------- fused attention: QK^T (MFMA) + mix + AV (MFMA), j-split partials ----------------
__global__ __launch_bounds__(256) void attn_kernel(
    const short* __restrict__ qn, const short* __restrict__ kn,
    const float* __restrict__ qkvd, const float* __restrict__ wat,
    float* __restrict__ partY, float* __restrict__ partZ)
{
    int h = threadIdx.x >> 6;                 // wave = head
    int lane = threadIdx.x & 63;
    int col = lane & 15, grp = lane >> 4;
    int itile = blockIdx.x;                   // 0..111
    int jc = blockIdx.y;                      // 0..JC_-1
    int b = blockIdx.z;
    int ibase = itile * 16;
    int bh = b * 4 + h;

    const short* qrow = qn + ((long)bh * S_ + ibase + col) * 64 + grp * 8;
    short8 qa0 = *(const short8*)qrow;
    short8 qa1 = *(const short8*)(qrow + 32);
    float wsc[4], wsh[4];
    #pragma unroll
    for (int hh = 0; hh < 4; ++hh) { wsc[hh] = wat[h * 4 + hh]; wsh[hh] = wat[(4 + h) * 4 + hh]; }

    __shared__ __align__(16) float exch[4][16][33];
    __shared__ __align__(16) short pbuf[4][2][16][40];

    f32x4 y1[4], y2[4];
    #pragma unroll
    for (int ds = 0; ds < 4; ++ds) {
        y1[ds] = (f32x4){0.f, 0.f, 0.f, 0.f};
        y2[ds] = (f32x4){0.f, 0.f, 0.f, 0.f};
    }
    float zp[4] = {0.f, 0.f, 0.f, 0.f};
    const short* kbase = kn + (long)bh * S_ * 64;
    const float* vbase = qkvd + ((long)b * 768 + 512 + h * 64) * S_;

    for (int jt = 0; jt < JSTEPS_; ++jt) {
        int jbase = jc * JRANGE_ + jt * 32;
        f32x4 lf[2];
        #pragma unroll
        for (int js = 0; js < 2; ++js) {
            const short* krow = kbase + (long)(jbase + js * 16 + col) * 64 + grp * 8;
            short8 kb0 = *(const short8*)krow;
            short8 kb1 = *(const short8*)(krow + 32);
            f32x4 a = (f32x4){0.f, 0.f, 0.f, 0.f};
            a = MFMA16(qa0, kb0, a);
            a = MFMA16(qa1, kb1, a);
            lf[js] = a;
        }
        // own-head a1 = gelu(relu(l)^2)*relu(l)^2, exchanged via LDS (computed once per h,i,j)
        float a1own[8];
        #pragma unroll
        for (int js = 0; js < 2; ++js)
            #pragma unroll
            for (int r = 0; r < 4; ++r) {
                float l = lf[js][r];
                float rr = fmaxf(l, 0.f);
                float s1 = rr * rr;
                float a1 = s1 * 0.5f * (1.f + erff(s1 * 0.70710678118654752f)) * s1;
                a1own[js * 4 + r] = a1;
                exch[h][grp * 4 + r][js * 16 + col] = a1;
            }
        __syncthreads();
        #pragma unroll
        for (int js = 0; js < 2; ++js)
            #pragma unroll
            for (int r = 0; r < 4; ++r) {
                float sc = 0.f, sh = 0.f;
                #pragma unroll
                for (int hh = 0; hh < 4; ++hh) {
                    float a1v = (hh == h) ? a1own[js * 4 + r]
                                          : exch[hh][grp * 4 + r][js * 16 + col];
                    sc += a1v * wsc[hh];
                    sh += a1v * wsh[hh];
                }
                float e = __expf(lf[js][r]);
                zp[r] += e;
                pbuf[h][0][grp * 4 + r][js * 16 + col] = f2bf(e * (1.f + sc));
                pbuf[h][1][grp * 4 + r][js * 16 + col] = f2bf(sh);
            }
        __syncthreads();
        short8 p1a = *(const short8*)&pbuf[h][0][col][grp * 8];
        short8 p2a = *(const short8*)&pbuf[h][1][col][grp * 8];
        #pragma unroll
        for (int ds = 0; ds < 4; ++ds) {
            const float* vrow = vbase + (long)(ds * 16 + col) * S_ + jbase + grp * 8;
            f32x4 v0 = *(const f32x4*)vrow;
            f32x4 v1 = *(const f32x4*)(vrow + 4);
            short8 vb;
            vb[0] = f2bf(v0[0]); vb[1] = f2bf(v0[1]); vb[2] = f2bf(v0[2]); vb[3] = f2bf(v0[3]);
            vb[4] = f2bf(v1[0]); vb[5] = f2bf(v1[1]); vb[6] = f2bf(v1[2]); vb[7] = f2bf(v1[3]);
            y1[ds] = MFMA16(p1a, vb, y1[ds]);
            y2[ds] = MFMA16(p2a, vb, y2[ds]);
        }
    }

    // Z: reduce over the 16 lanes covering the row's columns
    #pragma unroll
    for (int o = 1; o < 16; o <<= 1) {
        #pragma unroll
        for (int r = 0; r < 4; ++r) zp[r] += __shfl_xor(zp[r], o, 64);
    }
    if (col == 0) {
        #pragma unroll
        for (int r = 0; r < 4; ++r)
            partZ[((long)(jc * 2 + b) * 4 + h) * S_ + ibase + grp * 4 + r] = zp[r];
    }
    // transpose D-frags via LDS, write partY[jc][b][h][acc][d][i] coalesced over i
    float* tb = &exch[h][0][0];               // wave-private scratch, 16x17 layout
    long ybase = ((((long)jc * 2 + b) * 4 + h) * 2) * 64 * S_;
    for (int acc = 0; acc < 2; ++acc) {
        #pragma unroll
        for (int ds = 0; ds < 4; ++ds) {
            f32x4 y = acc ? y2[ds] : y1[ds];
            #pragma unroll
            for (int r = 0; r < 4; ++r) tb[col * 17 + grp * 4 + r] = y[r];
            #pragma unroll
            for (int p = 0; p < 4; ++p) {
                float val = tb[(p * 4 + grp) * 17 + col];
                partY[ybase + ((long)acc * 64 + ds * 16 + p * 4 + grp) * S_ + ibase + col] = val;
            }
        }
    }
}

// ---------------- combine j-chunks: out = (sum Y1)/(sum Z) + sum Y2 ----------------
__global__ __launch_bounds__(256) void combine_kernel(
    const float* __restrict__ partY, const float* __restrict__ partZ,
    float* __restrict__ outav)
{
    int idx = blockIdx.x * 256 + threadIdx.x;   // ((b*4+h)*64+d)*S + i
    int i = idx % S_;
    int t = idx / S_;
    int d = t & 63; t >>= 6;
    int h = t & 3; int b = t >> 2;
    float y1 = 0.f, y2 = 0.f, z = 0.f;
    #pragma unroll
    for (int jc = 0; jc < JC_; ++jc) {
        long base = ((((long)jc * 2 + b) * 4 + h) * 2) * 64 * S_;
        y1 += partY[base + (long)d * S_ + i];
        y2 += partY[base + (long)(64 + d) * S_ + i];
        z  += partZ[((long)(jc * 2 + b) * 4 + h) * S_ + i];
    }
    outav[((long)b * 256 + h * 64 + d) * S_ + i] = y1 / z + y2;
}

// ---------------- residual add (remap) + LN2 over C=4 + GDFN pin (hbuf bf16) ----------------
__global__ __launch_bounds__(256) void resid_pin_kernel(
    const float* __restrict__ buffer, const float* __restrict__ proj,
    const float* __restrict__ g2, const float* __restrict__ b2,
    const float* __restrict__ w_pin,
    float* __restrict__ x2, short* __restrict__ hbuf)
{
    int s = blockIdx.x * 256 + threadIdx.x;
    int bn = blockIdx.y;
    int b = bn / N_, n = bn % N_;
    float v[4];
    float sum = 0.f;
    #pragma unroll
    for (int c = 0; c < 4; ++c) {
        float xr = buffer[((long)(b * 4 + c) * N_ + n) * S_ + s];
        float pr = proj[((long)b * TOK_ + c * N_ + n) * S_ + s];
        v[c] = xr + pr;
        x2[((long)bn * 4 + c) * S_ + s] = v[c];
        sum += v[c];
    }
    float mean = sum * 0.25f;
    float var = 0.f;
    #pragma unroll
    for (int c = 0; c < 4; ++c) { float dd = v[c] - mean; var += dd * dd; }
    var *= 0.25f;
    float inv = rsqrtf(var + 1e-6f);
    float e[4];
    #pragma unroll
    for (int c = 0; c < 4; ++c) e[c] = (v[c] - mean) * inv * g2[c] + b2[c];
    for (int o = 0; o < 2 * HF_; ++o) {
        float a = 0.f;
        #pragma unroll
        for (int c = 0; c < 4; ++c) a += w_pin[o * 4 + c] * e[c];
        hbuf[((long)bn * (2 * HF_) + o) * S_ + s] = f2bf(a);
    }
}

// ------- fused GDFN tail: dwconv3(hbuf bf16) + gelu-gate + pout + residual + remap -------
__global__ __launch_bounds__(448) void gdfn_kernel(
    const short* __restrict__ hbuf, const float* __restrict__ w_dw,
    const float* __restrict__ w_pout, const float* __restrict__ x2,
    float* __restrict__ out)
{
    int xt = blockIdx.x;             // 0..3 (64-wide x tiles)
    int bn = blockIdx.y;             // 0..447
    int b = bn / N_, n = bn % N_;
    int x0 = xt * 64;
    __shared__ float tile[20][7][66];
    int tid = threadIdx.x;
    for (int idx = tid; idx < 20 * 7 * 66; idx += 448) {
        int ch = idx / (7 * 66); int rem = idx % (7 * 66);
        int y = rem / 66; int xx = rem % 66;
        int gx = x0 + xx - 1;
        float v = 0.f;
        if (gx >= 0 && gx < W_) v = bf2f(hbuf[((long)bn * 20 + ch) * S_ + y * W_ + gx]);
        tile[ch][y][xx] = v;
    }
    __syncthreads();
    int y = tid / 64, x = tid & 63;
    float hd[20];
    #pragma unroll
    for (int ch = 0; ch < 20; ++ch) {
        const float* wp = w_dw + ch * 9;
        float acc = 0.f;
        #pragma unroll
        for (int dy = -1; dy <= 1; ++dy) {
            int yy = y + dy;
            if (yy < 0 || yy >= V_) continue;
            #pragma unroll
            for (int dx = -1; dx <= 1; ++dx)
                acc += tile[ch][yy][x + 1 + dx] * wp[(dy + 1) * 3 + (dx + 1)];
        }
        hd[ch] = acc;
    }
    float g[HF_];
    #pragma unroll
    for (int f = 0; f < HF_; ++f) {
        float h1 = hd[f];
        g[f] = 0.5f * h1 * (1.f + erff(h1 * 0.70710678118654752f)) * hd[HF_ + f];
    }
    int s = y * W_ + x0 + x;
    #pragma unroll
    for (int c = 0; c < 4; ++c) {
        float a = 0.f;
        #pragma unroll
        for (int f = 0; f < HF_; ++f) a += w_pout[c * HF_ + f] * g[f];
        out[((long)(b * 4 + c) * N_ + n) * S_ + s] = x2[((long)bn * 4 + c) * S_ + s] + a;
    }
}

extern "C" void kernel_launch(void* const* d_in, const int* in_sizes, int n_in,
                              void* d_out, int out_size, void* d_ws, size_t ws_size,
                              hipStream_t stream)
{
    const float* buffer = (const float*)d_in[0];
    const float* w_in   = (const float*)d_in[1];
    const float* temp   = (const float*)d_in[2];
    const float* ln1_g  = (const float*)d_in[3];
    const float* ln1_b  = (const float*)d_in[4];
    const float* w_qkv  = (const float*)d_in[5];
    const float* w_qkv_dw = (const float*)d_in[6];
    const float* w_proj = (const float*)d_in[7];
    const float* w_attca = (const float*)d_in[8];
    const float* ln2_g  = (const float*)d_in[9];
    const float* ln2_b  = (const float*)d_in[10];
    const float* w_pin  = (const float*)d_in[11];
    const float* w_dw   = (const float*)d_in[12];
    const float* w_pout = (const float*)d_in[13];
    float* out = (float*)d_out;

    float* ws = (float*)d_ws;
    float* qkvd    = ws;                        // 2,752,512
    short* qn      = (short*)(ws + 2752512);    // 917,504 bf16
    short* kn      = (short*)(ws + 3211264);    // 917,504 bf16
    float* partY   = ws + 3670016;              // 3,670,016
    float* partZ   = ws + 7340032;              // 28,672
    float* outav   = ws + 7368704;              // 917,504
    float* xw      = ws + 8286208;              // 917,504
    float* xn      = ws + 9203712;              // 917,504
    float* qkv     = ws + 10121216;             // 2,752,512
    float* outproj = ws + 12873728;             // 3,211,264
    float* x2      = ws + 16084992;             // 3,211,264
    short* hbuf    = (short*)(ws + 19296256);   // 16,056,320 bf16
    // end: 27,324,416 floats = 109.3 MB

    // 1. linear_in (bf16 MFMA): xw[b][256][S] = w_in[256][896] x buffer[b][896][S]
    gemm_mfma_kernel<<<dim3(14, 2, 2), 256, 0, stream>>>(
        w_in, buffer, xw, EMB_, S_, TOK_, (long)TOK_ * S_, (long)EMB_ * S_);

    // 2. LN1
    ln1_kernel<<<dim3(28, 2), 256, 0, stream>>>(xw, ln1_g, ln1_b, xn);

    // 3. qkv 1x1 conv (bf16 MFMA)
    gemm_mfma_kernel<<<dim3(14, 6, 2), 256, 0, stream>>>(
        w_qkv, xn, qkv, 3 * EMB_, S_, EMB_, (long)EMB_ * S_, (long)3 * EMB_ * S_);

    // 4. depthwise 3x3 on qkv
    {
        long total = (long)B_ * 3 * EMB_ * S_;
        dwconv3_kernel<<<(int)((total + 255) / 256), 256, 0, stream>>>(
            qkv, w_qkv_dw, qkvd, total, 3 * EMB_);
    }

    // 5. q,k -> normalized bf16 (temp folded into q)
    headnorm_kernel<<<dim3(28, 8, 2), 256, 0, stream>>>(qkvd, temp, qn, kn);

    // 6. fused attention partials
    attn_kernel<<<dim3(112, JC_, B_), 256, 0, stream>>>(qn, kn, qkvd, w_attca, partY, partZ);

    // 7. combine partials -> outav
    combine_kernel<<<3584, 256, 0, stream>>>(partY, partZ, outav);

    // 8. proj (bf16 MFMA)
    gemm_mfma_kernel<<<dim3(14, 7, 2), 256, 0, stream>>>(
        w_proj, outav, outproj, TOK_, S_, EMB_, (long)EMB_ * S_, (long)TOK_ * S_);

    // 9. residual + LN2 + GDFN pin (bf16 hbuf)
    resid_pin_kernel<<<dim3(7, B_ * N_), 256, 0, stream>>>(
        buffer, outproj, ln2_g, ln2_b, w_pin, x2, hbuf);

    // 10. fused GDFN tail
    gdfn_kernel<<<dim3(4, B_ * N_), 448, 0, stream>>>(hbuf, w_dw, w_pout, x2, out);
}

// Round 4
// 228.421 us; speedup vs baseline: 5.2494x; 1.2342x over previous
//
#include <hip/hip_runtime.h>
#include <math.h>

#define B_ 2
#define C_ 4
#define N_ 224
#define V_ 7
#define W_ 256
#define S_ 1792
#define EMB_ 256
#define H_ 4
#define D_ 64
#define TOK_ 896
#define HF_ 10
#define JC_ 4
#define JRANGE_ (S_ / JC_)      /* 448 */
#define JSTEPS_ (JRANGE_ / 32)  /* 14 */

typedef __attribute__((ext_vector_type(8))) short short8;
typedef __attribute__((ext_vector_type(4))) short bf16x4;
typedef __attribute__((ext_vector_type(4))) float f32x4;

#define MFMA16(a, b, c) __builtin_amdgcn_mfma_f32_16x16x32_bf16(a, b, c, 0, 0, 0)

__device__ inline short f2bf(float f) {
    union { float f; unsigned u; } x; x.f = f;
    unsigned u = x.u;
    unsigned r = (u + 0x7fffu + ((u >> 16) & 1u)) >> 16;
    return (short)r;
}
__device__ inline float bf2f(short s) {
    union { unsigned u; float f; } x;
    x.u = ((unsigned)(unsigned short)s) << 16;
    return x.f;
}

// ------------- bf16 MFMA GEMM: C[b][M][N] = A[M][K](fp32) x Bact[b][K][N](fp32) -------------
__global__ __launch_bounds__(256) void gemm_mfma_kernel(
    const float* __restrict__ A, const float* __restrict__ Bact, float* __restrict__ Cm,
    int M, int N, int K, long b_bs, long c_bs)
{
    Bact += (long)blockIdx.z * b_bs;
    Cm   += (long)blockIdx.z * c_bs;
    const int m0 = blockIdx.y * 128, n0 = blockIdx.x * 128;
    __shared__ __align__(16) short As[128][40];   // [m][k], pad 32->40
    __shared__ __align__(16) short Bs[128][40];   // [n][k], pad 32->40
    const int t = threadIdx.x;
    const int lane = t & 63;
    const int wave = t >> 6;
    const int wr = wave >> 1, wc = wave & 1;
    const int col = lane & 15, grp = lane >> 4;
    const int ar = t >> 3, ak = (t & 7) * 4;
    const int bn = t & 127, kb = (t >> 7) * 16;
    f32x4 acc[4][4];
    #pragma unroll
    for (int i = 0; i < 4; ++i)
        #pragma unroll
        for (int j = 0; j < 4; ++j) acc[i][j] = (f32x4){0.f, 0.f, 0.f, 0.f};
    for (int k0 = 0; k0 < K; k0 += 32) {
        #pragma unroll
        for (int p = 0; p < 4; ++p) {
            f32x4 v = *(const f32x4*)&A[(long)(m0 + ar + p * 32) * K + k0 + ak];
            bf16x4 pk;
            pk[0] = f2bf(v[0]); pk[1] = f2bf(v[1]); pk[2] = f2bf(v[2]); pk[3] = f2bf(v[3]);
            *(bf16x4*)&As[ar + p * 32][ak] = pk;
        }
        float tv[16];
        #pragma unroll
        for (int j = 0; j < 16; ++j)
            tv[j] = Bact[(long)(k0 + kb + j) * N + n0 + bn];
        short8 b0, b1;
        #pragma unroll
        for (int j = 0; j < 8; ++j) { b0[j] = f2bf(tv[j]); b1[j] = f2bf(tv[8 + j]); }
        *(short8*)&Bs[bn][kb]     = b0;
        *(short8*)&Bs[bn][kb + 8] = b1;
        __syncthreads();
        short8 af[4], bfr[4];
        #pragma unroll
        for (int m16 = 0; m16 < 4; ++m16)
            af[m16] = *(const short8*)&As[wr * 64 + m16 * 16 + col][grp * 8];
        #pragma unroll
        for (int n16 = 0; n16 < 4; ++n16)
            bfr[n16] = *(const short8*)&Bs[wc * 64 + n16 * 16 + col][grp * 8];
        #pragma unroll
        for (int m16 = 0; m16 < 4; ++m16)
            #pragma unroll
            for (int n16 = 0; n16 < 4; ++n16)
                acc[m16][n16] = MFMA16(af[m16], bfr[n16], acc[m16][n16]);
        __syncthreads();
    }
    #pragma unroll
    for (int m16 = 0; m16 < 4; ++m16)
        #pragma unroll
        for (int n16 = 0; n16 < 4; ++n16)
            #pragma unroll
            for (int r = 0; r < 4; ++r)
                Cm[(long)(m0 + wr * 64 + m16 * 16 + grp * 4 + r) * N
                   + n0 + wc * 64 + n16 * 16 + col] = acc[m16][n16][r];
}

// ---------------- LN1 over 256 channels ----------------
__global__ __launch_bounds__(256) void ln1_kernel(
    const float* __restrict__ X, const float* __restrict__ g,
    const float* __restrict__ b, float* __restrict__ Y)
{
    int sl = threadIdx.x & 63, dg = threadIdx.x >> 6;
    int s = blockIdx.x * 64 + sl;
    int img = blockIdx.y;
    const float* xp = X + (long)img * EMB_ * S_ + s;
    float sum = 0.f, sq = 0.f;
    for (int c = dg * 64; c < dg * 64 + 64; ++c) {
        float v = xp[(long)c * S_];
        sum += v; sq += v * v;
    }
    __shared__ float rs[64][5], rq[64][5];
    rs[sl][dg] = sum; rq[sl][dg] = sq;
    __syncthreads();
    float tot = rs[sl][0] + rs[sl][1] + rs[sl][2] + rs[sl][3];
    float tq  = rq[sl][0] + rq[sl][1] + rq[sl][2] + rq[sl][3];
    float mean = tot * (1.f / EMB_);
    float var  = tq * (1.f / EMB_) - mean * mean;
    float inv  = rsqrtf(var + 1e-6f);
    float* yp = Y + (long)img * EMB_ * S_ + s;
    for (int c = dg * 64; c < dg * 64 + 64; ++c)
        yp[(long)c * S_] = (xp[(long)c * S_] - mean) * inv * g[c] + b[c];
}

// ------- depthwise 3x3, SAME; V channels (512..767) also emitted as bf16 [b][256][S] -------
__global__ void dwconv3_kernel(const float* __restrict__ X, const float* __restrict__ Wt,
                               float* __restrict__ Y, short* __restrict__ vbf,
                               long total, int Ch)
{
    long idx = (long)blockIdx.x * blockDim.x + threadIdx.x;
    long stride = (long)gridDim.x * blockDim.x;
    for (; idx < total; idx += stride) {
        int w = (int)(idx % W_);
        long t = idx / W_;
        int h = (int)(t % V_); t /= V_;
        int ch = (int)(t % Ch);
        long img_ch = idx / ((long)V_ * W_);
        const float* wp = Wt + ch * 9;
        const float* xp = X + img_ch * (V_ * W_);
        float acc = 0.f;
        #pragma unroll
        for (int dy = -1; dy <= 1; ++dy) {
            int h2 = h + dy;
            if (h2 < 0 || h2 >= V_) continue;
            #pragma unroll
            for (int dx = -1; dx <= 1; ++dx) {
                int w2 = w + dx;
                if (w2 < 0 || w2 >= W_) continue;
                acc += xp[h2 * W_ + w2] * wp[(dy + 1) * 3 + (dx + 1)];
            }
        }
        Y[idx] = acc;
        if (vbf && ch >= 512) {
            int b = (int)(t / Ch);
            vbf[((long)b * 256 + (ch - 512)) * S_ + h * W_ + w] = f2bf(acc);
        }
    }
}

// ------- head transpose + L2-normalize -> bf16 [B][H][S][64]; q also scaled by temp -------
__global__ __launch_bounds__(256) void headnorm_kernel(
    const float* __restrict__ qkvd, const float* __restrict__ temp,
    short* __restrict__ qn, short* __restrict__ kn)
{
    int s0 = blockIdx.x * 64;
    int bh = blockIdx.y; int b = bh >> 2, h = bh & 3;
    int isq = blockIdx.z;                    // 0 = k, 1 = q
    int ch0 = b * 768 + (isq ? 0 : EMB_) + h * 64;
    short* dst = (isq ? qn : kn) + (long)bh * S_ * 64;
    __shared__ float tile[64][65];
    __shared__ float red[64][4];
    int t = threadIdx.x;
    int sl = t & 63, dg = t >> 6;
    float part = 0.f;
    for (int dd = 0; dd < 16; ++dd) {
        int d = dg * 16 + dd;
        float v = qkvd[(long)(ch0 + d) * S_ + s0 + sl];
        tile[sl][d] = v;
        part += v * v;
    }
    red[sl][dg] = part;
    __syncthreads();
    int d = t & 63, sg = t >> 6;
    float tmul = isq ? temp[h] : 1.f;
    for (int si = 0; si < 16; ++si) {
        int s = sg * 16 + si;
        float nrm = sqrtf(red[s][0] + red[s][1] + red[s][2] + red[s][3]);
        float scale = tmul / fmaxf(nrm, 1e-12f);
        dst[(long)(s0 + s) * 64 + d] = f2bf(tile[s][d] * scale);
    }
}

// ---------------- fused attention: QK^T (MFMA) + mix + AV (MFMA), j-split partials ----------------
__global__ __launch_bounds__(256) void attn_kernel(
    const short* __restrict__ qn, const short* __restrict__ kn,
    const short* __restrict__ vbf, const float* __restrict__ wat,
    float* __restrict__ partY, float* __restrict__ partZ)
{
    int h = threadIdx.x >> 6;                 // wave = head
    int lane = threadIdx.x & 63;
    int col = lane & 15, grp = lane >> 4;
    int itile = blockIdx.x;                   // 0..111
    int jc = blockIdx.y;                      // 0..JC_-1
    int b = blockIdx.z;
    int ibase = itile * 16;
    int bh = b * 4 + h;

    const short* qrow = qn + ((long)bh * S_ + ibase + col) * 64 + grp * 8;
    short8 qa0 = *(const short8*)qrow;
    short8 qa1 = *(const short8*)(qrow + 32);
    float wsc[4], wsh[4];
    #pragma unroll
    for (int hh = 0; hh < 4; ++hh) { wsc[hh] = wat[h * 4 + hh]; wsh[hh] = wat[(4 + h) * 4 + hh]; }

    __shared__ __align__(16) float exch[4][16][33];
    __shared__ __align__(16) short pbuf[4][2][16][40];

    f32x4 y1[4], y2[4];
    #pragma unroll
    for (int ds = 0; ds < 4; ++ds) {
        y1[ds] = (f32x4){0.f, 0.f, 0.f, 0.f};
        y2[ds] = (f32x4){0.f, 0.f, 0.f, 0.f};
    }
    float zp[4] = {0.f, 0.f, 0.f, 0.f};
    const short* kbase = kn + (long)bh * S_ * 64;
    const short* vbase = vbf + ((long)b * 256 + h * 64) * S_;

    for (int jt = 0; jt < JSTEPS_; ++jt) {
        int jbase = jc * JRANGE_ + jt * 32;
        f32x4 lf[2];
        #pragma unroll
        for (int js = 0; js < 2; ++js) {
            const short* krow = kbase + (long)(jbase + js * 16 + col) * 64 + grp * 8;
            short8 kb0 = *(const short8*)krow;
            short8 kb1 = *(const short8*)(krow + 32);
            f32x4 a = (f32x4){0.f, 0.f, 0.f, 0.f};
            a = MFMA16(qa0, kb0, a);
            a = MFMA16(qa1, kb1, a);
            lf[js] = a;
        }
        float a1own[8];
        #pragma unroll
        for (int js = 0; js < 2; ++js)
            #pragma unroll
            for (int r = 0; r < 4; ++r) {
                float l = lf[js][r];
                float rr = fmaxf(l, 0.f);
                float s1 = rr * rr;
                float a1 = s1 * 0.5f * (1.f + erff(s1 * 0.70710678118654752f)) * s1;
                a1own[js * 4 + r] = a1;
                exch[h][grp * 4 + r][js * 16 + col] = a1;
            }
        __syncthreads();
        #pragma unroll
        for (int js = 0; js < 2; ++js)
            #pragma unroll
            for (int r = 0; r < 4; ++r) {
                float sc = 0.f, sh = 0.f;
                #pragma unroll
                for (int hh = 0; hh < 4; ++hh) {
                    float a1v = (hh == h) ? a1own[js * 4 + r]
                                          : exch[hh][grp * 4 + r][js * 16 + col];
                    sc += a1v * wsc[hh];
                    sh += a1v * wsh[hh];
                }
                float e = __expf(lf[js][r]);
                zp[r] += e;
                pbuf[h][0][grp * 4 + r][js * 16 + col] = f2bf(e * (1.f + sc));
                pbuf[h][1][grp * 4 + r][js * 16 + col] = f2bf(sh);
            }
        __syncthreads();
        short8 p1a = *(const short8*)&pbuf[h][0][col][grp * 8];
        short8 p2a = *(const short8*)&pbuf[h][1][col][grp * 8];
        #pragma unroll
        for (int ds = 0; ds < 4; ++ds) {
            const short* vrow = vbase + (long)(ds * 16 + col) * S_ + jbase + grp * 8;
            short8 vb = *(const short8*)vrow;
            y1[ds] = MFMA16(p1a, vb, y1[ds]);
            y2[ds] = MFMA16(p2a, vb, y2[ds]);
        }
    }

    #pragma unroll
    for (int o = 1; o < 16; o <<= 1) {
        #pragma unroll
        for (int r = 0; r < 4; ++r) zp[r] += __shfl_xor(zp[r], o, 64);
    }
    if (col == 0) {
        #pragma unroll
        for (int r = 0; r < 4; ++r)
            partZ[((long)(jc * 2 + b) * 4 + h) * S_ + ibase + grp * 4 + r] = zp[r];
    }
    float* tb = &exch[h][0][0];
    long ybase = ((((long)jc * 2 + b) * 4 + h) * 2) * 64 * S_;
    for (int acc = 0; acc < 2; ++acc) {
        #pragma unroll
        for (int ds = 0; ds < 4; ++ds) {
            f32x4 y = acc ? y2[ds] : y1[ds];
            #pragma unroll
            for (int r = 0; r < 4; ++r) tb[col * 17 + grp * 4 + r] = y[r];
            #pragma unroll
            for (int p = 0; p < 4; ++p) {
                float val = tb[(p * 4 + grp) * 17 + col];
                partY[ybase + ((long)acc * 64 + ds * 16 + p * 4 + grp) * S_ + ibase + col] = val;
            }
        }
    }
}

// ---------------- combine j-chunks: out = (sum Y1)/(sum Z) + sum Y2 ----------------
__global__ __launch_bounds__(256) void combine_kernel(
    const float* __restrict__ partY, const float* __restrict__ partZ,
    float* __restrict__ outav)
{
    int idx = blockIdx.x * 256 + threadIdx.x;
    int i = idx % S_;
    int t = idx / S_;
    int d = t & 63; t >>= 6;
    int h = t & 3; int b = t >> 2;
    float y1 = 0.f, y2 = 0.f, z = 0.f;
    #pragma unroll
    for (int jc = 0; jc < JC_; ++jc) {
        long base = ((((long)jc * 2 + b) * 4 + h) * 2) * 64 * S_;
        y1 += partY[base + (long)d * S_ + i];
        y2 += partY[base + (long)(64 + d) * S_ + i];
        z  += partZ[((long)(jc * 2 + b) * 4 + h) * S_ + i];
    }
    outav[((long)b * 256 + h * 64 + d) * S_ + i] = y1 / z + y2;
}

// ---------------- residual add (remap) + LN2 over C=4 + GDFN pin (hbuf bf16) ----------------
__global__ __launch_bounds__(256) void resid_pin_kernel(
    const float* __restrict__ buffer, const float* __restrict__ proj,
    const float* __restrict__ g2, const float* __restrict__ b2,
    const float* __restrict__ w_pin,
    float* __restrict__ x2, short* __restrict__ hbuf)
{
    int s = blockIdx.x * 256 + threadIdx.x;
    int bn = blockIdx.y;
    int b = bn / N_, n = bn % N_;
    float v[4];
    float sum = 0.f;
    #pragma unroll
    for (int c = 0; c < 4; ++c) {
        float xr = buffer[((long)(b * 4 + c) * N_ + n) * S_ + s];
        float pr = proj[((long)b * TOK_ + c * N_ + n) * S_ + s];
        v[c] = xr + pr;
        x2[((long)bn * 4 + c) * S_ + s] = v[c];
        sum += v[c];
    }
    float mean = sum * 0.25f;
    float var = 0.f;
    #pragma unroll
    for (int c = 0; c < 4; ++c) { float dd = v[c] - mean; var += dd * dd; }
    var *= 0.25f;
    float inv = rsqrtf(var + 1e-6f);
    float e[4];
    #pragma unroll
    for (int c = 0; c < 4; ++c) e[c] = (v[c] - mean) * inv * g2[c] + b2[c];
    for (int o = 0; o < 2 * HF_; ++o) {
        float a = 0.f;
        #pragma unroll
        for (int c = 0; c < 4; ++c) a += w_pin[o * 4 + c] * e[c];
        hbuf[((long)bn * (2 * HF_) + o) * S_ + s] = f2bf(a);
    }
}

// ------- fused GDFN tail: dwconv3(hbuf bf16) + gelu-gate + pout + residual + remap -------
__global__ __launch_bounds__(448) void gdfn_kernel(
    const short* __restrict__ hbuf, const float* __restrict__ w_dw,
    const float* __restrict__ w_pout, const float* __restrict__ x2,
    float* __restrict__ out)
{
    int xt = blockIdx.x;             // 0..3 (64-wide x tiles)
    int bn = blockIdx.y;             // 0..447
    int b = bn / N_, n = bn % N_;
    int x0 = xt * 64;
    __shared__ float tile[20][7][66];
    int tid = threadIdx.x;
    for (int idx = tid; idx < 20 * 7 * 66; idx += 448) {
        int ch = idx / (7 * 66); int rem = idx % (7 * 66);
        int y = rem / 66; int xx = rem % 66;
        int gx = x0 + xx - 1;
        float v = 0.f;
        if (gx >= 0 && gx < W_) v = bf2f(hbuf[((long)bn * 20 + ch) * S_ + y * W_ + gx]);
        tile[ch][y][xx] = v;
    }
    __syncthreads();
    int y = tid / 64, x = tid & 63;
    float hd[20];
    #pragma unroll
    for (int ch = 0; ch < 20; ++ch) {
        const float* wp = w_dw + ch * 9;
        float acc = 0.f;
        #pragma unroll
        for (int dy = -1; dy <= 1; ++dy) {
            int yy = y + dy;
            if (yy < 0 || yy >= V_) continue;
            #pragma unroll
            for (int dx = -1; dx <= 1; ++dx)
                acc += tile[ch][yy][x + 1 + dx] * wp[(dy + 1) * 3 + (dx + 1)];
        }
        hd[ch] = acc;
    }
    float g[HF_];
    #pragma unroll
    for (int f = 0; f < HF_; ++f) {
        float h1 = hd[f];
        g[f] = 0.5f * h1 * (1.f + erff(h1 * 0.70710678118654752f)) * hd[HF_ + f];
    }
    int s = y * W_ + x0 + x;
    #pragma unroll
    for (int c = 0; c < 4; ++c) {
        float a = 0.f;
        #pragma unroll
        for (int f = 0; f < HF_; ++f) a += w_pout[c * HF_ + f] * g[f];
        out[((long)(b * 4 + c) * N_ + n) * S_ + s] = x2[((long)bn * 4 + c) * S_ + s] + a;
    }
}

extern "C" void kernel_launch(void* const* d_in, const int* in_sizes, int n_in,
                              void* d_out, int out_size, void* d_ws, size_t ws_size,
                              hipStream_t stream)
{
    const float* buffer = (const float*)d_in[0];
    const float* w_in   = (const float*)d_in[1];
    const float* temp   = (const float*)d_in[2];
    const float* ln1_g  = (const float*)d_in[3];
    const float* ln1_b  = (const float*)d_in[4];
    const float* w_qkv  = (const float*)d_in[5];
    const float* w_qkv_dw = (const float*)d_in[6];
    const float* w_proj = (const float*)d_in[7];
    const float* w_attca = (const float*)d_in[8];
    const float* ln2_g  = (const float*)d_in[9];
    const float* ln2_b  = (const float*)d_in[10];
    const float* w_pin  = (const float*)d_in[11];
    const float* w_dw   = (const float*)d_in[12];
    const float* w_pout = (const float*)d_in[13];
    float* out = (float*)d_out;

    float* ws = (float*)d_ws;
    float* qkvd    = ws;                        // 2,752,512
    short* qn      = (short*)(ws + 2752512);    // 917,504 bf16
    short* kn      = (short*)(ws + 3211264);    // 917,504 bf16
    short* vbf     = (short*)(ws + 3670016);    // 917,504 bf16
    float* partY   = ws + 4128768;              // 7,340,032
    float* partZ   = ws + 11468800;             // 57,344
    float* outav   = ws + 11526144;             // 917,504
    float* xw      = ws + 12443648;             // 917,504
    float* xn      = ws + 13361152;             // 917,504
    float* qkv     = ws + 14278656;             // 2,752,512
    float* outproj = ws + 17031168;             // 3,211,264
    float* x2      = ws + 20242432;             // 3,211,264
    short* hbuf    = (short*)(ws + 23453696);   // 16,056,320 bf16
    // end: 31,481,856 floats = 125.9 MB

    // 1. linear_in (bf16 MFMA)
    gemm_mfma_kernel<<<dim3(14, 2, 2), 256, 0, stream>>>(
        w_in, buffer, xw, EMB_, S_, TOK_, (long)TOK_ * S_, (long)EMB_ * S_);

    // 2. LN1
    ln1_kernel<<<dim3(28, 2), 256, 0, stream>>>(xw, ln1_g, ln1_b, xn);

    // 3. qkv 1x1 conv (bf16 MFMA)
    gemm_mfma_kernel<<<dim3(14, 6, 2), 256, 0, stream>>>(
        w_qkv, xn, qkv, 3 * EMB_, S_, EMB_, (long)EMB_ * S_, (long)3 * EMB_ * S_);

    // 4. depthwise 3x3 on qkv (+ bf16 V emit)
    {
        long total = (long)B_ * 3 * EMB_ * S_;
        dwconv3_kernel<<<(int)((total + 255) / 256), 256, 0, stream>>>(
            qkv, w_qkv_dw, qkvd, vbf, total, 3 * EMB_);
    }

    // 5. q,k -> normalized bf16 (temp folded into q)
    headnorm_kernel<<<dim3(28, 8, 2), 256, 0, stream>>>(qkvd, temp, qn, kn);

    // 6. fused attention partials (JC_=4 for occupancy)
    attn_kernel<<<dim3(112, JC_, B_), 256, 0, stream>>>(qn, kn, vbf, w_attca, partY, partZ);

    // 7. combine partials -> outav
    combine_kernel<<<3584, 256, 0, stream>>>(partY, partZ, outav);

    // 8. proj (bf16 MFMA)
    gemm_mfma_kernel<<<dim3(14, 7, 2), 256, 0, stream>>>(
        w_proj, outav, outproj, TOK_, S_, EMB_, (long)EMB_ * S_, (long)TOK_ * S_);

    // 9. residual + LN2 + GDFN pin (bf16 hbuf)
    resid_pin_kernel<<<dim3(7, B_ * N_), 256, 0, stream>>>(
        buffer, outproj, ln2_g, ln2_b, w_pin, x2, hbuf);

    // 10. fused GDFN tail
    gdfn_kernel<<<dim3(4, B_ * N_), 448, 0, stream>>>(hbuf, w_dw, w_pout, x2, out);
}